// Round 6
// baseline (1838.928 us; speedup 1.0000x reference)
//
#include <hip/hip_runtime.h>

static constexpr int TT = 512;   // sequence length
static constexpr int BB = 256;   // batch

// LDS-only barrier: no vmcnt(0) drain, so global loads stay in flight across
// it (T4/T14 pattern). lgkmcnt(0) makes prior LDS writes visible.
#define BARRIER() do { \
    asm volatile("s_waitcnt lgkmcnt(0)" ::: "memory"); \
    __builtin_amdgcn_s_barrier(); \
    asm volatile("" ::: "memory"); \
  } while (0)

__device__ __forceinline__ float sigmoid_fast(float v) {
  const float e = __builtin_amdgcn_exp2f(v * -1.44269504088896340736f);
  return __builtin_amdgcn_rcpf(1.0f + e);
}
__device__ __forceinline__ float dpp_add_xor1(float v) {
  const int p = __builtin_amdgcn_update_dpp(0, __builtin_bit_cast(int, v),
                                            0xB1, 0xF, 0xF, true);
  return v + __builtin_bit_cast(float, p);
}
__device__ __forceinline__ float dpp_add_xor2(float v) {
  const int p = __builtin_amdgcn_update_dpp(0, __builtin_bit_cast(int, v),
                                            0x4E, 0xF, 0xF, true);
  return v + __builtin_bit_cast(float, p);
}
__device__ __forceinline__ float swz_add_xor4(float v) {
  const int p = __builtin_amdgcn_ds_swizzle(__builtin_bit_cast(int, v), 0x101F);
  return v + __builtin_bit_cast(float, p);
}

// 128-FMA 4-gate dot over 8 float4 (SL=32), weights w[128]
#define DOT128(XV, W, AI, AF, AG, AO)                                        \
  _Pragma("unroll")                                                          \
  for (int jj = 0; jj < 8; ++jj) {                                           \
    const float4 v = (XV)[jj];                                               \
    const float* wj = &(W)[16 * jj];                                         \
    AI = fmaf(v.x, wj[0],  AI);  AF = fmaf(v.x, wj[1],  AF);                 \
    AG = fmaf(v.x, wj[2],  AG);  AO = fmaf(v.x, wj[3],  AO);                 \
    AI = fmaf(v.y, wj[4],  AI);  AF = fmaf(v.y, wj[5],  AF);                 \
    AG = fmaf(v.y, wj[6],  AG);  AO = fmaf(v.y, wj[7],  AO);                 \
    AI = fmaf(v.z, wj[8],  AI);  AF = fmaf(v.z, wj[9],  AF);                 \
    AG = fmaf(v.z, wj[10], AG);  AO = fmaf(v.z, wj[11], AO);                 \
    AI = fmaf(v.w, wj[12], AI);  AF = fmaf(v.w, wj[13], AF);                 \
    AG = fmaf(v.w, wj[14], AG);  AO = fmaf(v.w, wj[15], AO);                 \
  }

// 32-FMA 4-gate dot over 2 float4 (SL=8), weights w[32]
#define DOT32(XV, W, AI, AF, AG, AO)                                         \
  _Pragma("unroll")                                                          \
  for (int jj = 0; jj < 2; ++jj) {                                           \
    const float4 v = (XV)[jj];                                               \
    const float* wj = &(W)[16 * jj];                                         \
    AI = fmaf(v.x, wj[0],  AI);  AF = fmaf(v.x, wj[1],  AF);                 \
    AG = fmaf(v.x, wj[2],  AG);  AO = fmaf(v.x, wj[3],  AO);                 \
    AI = fmaf(v.y, wj[4],  AI);  AF = fmaf(v.y, wj[5],  AF);                 \
    AG = fmaf(v.y, wj[6],  AG);  AO = fmaf(v.y, wj[7],  AO);                 \
    AI = fmaf(v.z, wj[8],  AI);  AF = fmaf(v.z, wj[9],  AF);                 \
    AG = fmaf(v.z, wj[10], AG);  AO = fmaf(v.z, wj[11], AO);                 \
    AI = fmaf(v.w, wj[12], AI);  AF = fmaf(v.w, wj[13], AF);                 \
    AG = fmaf(v.w, wj[14], AG);  AO = fmaf(v.w, wj[15], AO);                 \
  }

// ===========================================================================
// Encoder fused: LSTM1 (64->128, seq) + LSTM2 (128->64, last state only).
// One block per batch row, 512 thr. LSTM2 runs 16 steps behind LSTM1.
// x@Wk1 and h1@Wk2 are chunk-GEMMed (8 steps/chunk) into double-buffered LDS
// with Wk streamed from L2 (8 dwords/thread/step); biases folded into accs.
// ===========================================================================
__global__ void __launch_bounds__(512, 2)
enc_fused(const float* __restrict__ x,     // [B,T,64]
          const float* __restrict__ Wk1,   // [64,512]
          const float* __restrict__ Wr1,   // [128,512]
          const float* __restrict__ b1,    // [512]
          const float* __restrict__ Wk2,   // [128,256]
          const float* __restrict__ Wr2,   // [64,256]
          const float* __restrict__ b2,    // [256]
          float* __restrict__ z_out)       // [B,64]
{
  const int tid = (int)threadIdx.x, b = (int)blockIdx.x;
  const int l  = tid & 63, wv = tid >> 6;
  const int sl1 = l & 3,  u1 = wv * 16 + (l >> 2);   // L1: NSu=4, H=128
  const int sl2 = l & 7,  u2 = wv * 8  + (l >> 3);   // L2: NSu=8, H=64
  const int c1 = tid;                                 // gemm1 column (512)
  const int c2 = tid & 255, hf = tid >> 8;            // gemm2 column + K-half

  __shared__ __align__(16) float zx1[2][8][512];      // x@Wk1+b1 chunks (32 KB)
  __shared__ __align__(16) float h1c[2][8][128];      // h1 chunks (8 KB)
  __shared__ __align__(16) float zx2[2][2][8][256];   // h1@Wk2 partials (32 KB)
  __shared__ __align__(16) float hb2[2][64];          // h2 ping-pong

  // resident recurrent weights
  float w1[128];
  #pragma unroll
  for (int i = 0; i < 32; ++i) {
    const float* col = Wr1 + (size_t)(sl1 * 32 + i) * 512;
    #pragma unroll
    for (int g = 0; g < 4; ++g) w1[i * 4 + g] = col[g * 128 + u1];
  }
  float w2[32];
  #pragma unroll
  for (int i = 0; i < 8; ++i) {
    const float* col = Wr2 + (size_t)(sl2 * 8 + i) * 256;
    #pragma unroll
    for (int g = 0; g < 4; ++g) w2[i * 4 + g] = col[g * 64 + u2];
  }
  const float b1c = b1[c1];
  const float b2c = (hf == 0) ? b2[c2] : 0.f;

  if (tid < 128) h1c[1][7][tid] = 0.f;   // h1(-1) = 0
  if (tid < 64)  hb2[1][tid]    = 0.f;   // h2(-1) = 0

  float zxa[8], zxa2[8];
  #pragma unroll
  for (int r = 0; r < 8; ++r) { zxa[r] = b1c; zxa2[r] = b2c; }

  float cst1 = 0.f, cst2 = 0.f;
  const float* xb = x + (size_t)b * TT * 64;
  BARRIER();

  for (int t = -8; t < 528; ++t) {
    const int j  = t & 7;
    const int ch = t >> 3;                 // arithmetic shift (t<0 -> -1)
    const bool g1 = (t < 504);             // gemm1 builds chunk ch+1 (0..63)
    const bool g2 = (t >= 8 && t < 520);   // gemm2 builds chunk ch-1
    const bool r1 = (t >= 0 && t < TT);    // LSTM1 step t
    const int  s  = t - 16;                // LSTM2 step
    const bool r2 = (s >= 0 && s < TT);

    // ---- early VMEM: streamed Wk slices for this step ----
    float wk1r[8], wk2r[8];
    if (g1) {
      #pragma unroll
      for (int i = 0; i < 8; ++i) wk1r[i] = Wk1[(size_t)(8 * j + i) * 512 + c1];
    }
    if (g2) {
      #pragma unroll
      for (int i = 0; i < 8; ++i)
        wk2r[i] = Wk2[(size_t)(hf * 64 + 8 * j + i) * 256 + c2];
    }

    // ---- LSTM1 recurrence ----
    if (r1) {
      const int row = t & 7,        buf  = ch & 1;
      const int prow = (t - 1) & 7, pbuf = ((t - 1) >> 3) & 1;
      const float4* xv = (const float4*)&h1c[pbuf][prow][sl1 * 32];
      const float zq = zx1[buf][row][sl1 * 128 + u1];
      float ai = (sl1 == 0) ? zq : 0.f;
      float af = (sl1 == 1) ? zq : 0.f;
      float ag = (sl1 == 2) ? zq : 0.f;
      float ao = (sl1 == 3) ? zq : 0.f;
      DOT128(xv, w1, ai, af, ag, ao);
      ai = dpp_add_xor1(ai); af = dpp_add_xor1(af);
      ag = dpp_add_xor1(ag); ao = dpp_add_xor1(ao);
      ai = dpp_add_xor2(ai); af = dpp_add_xor2(af);
      ag = dpp_add_xor2(ag); ao = dpp_add_xor2(ao);
      const float gi = sigmoid_fast(ai);
      const float gf = sigmoid_fast(af);
      const float go = sigmoid_fast(ao);
      const float gg = fmaxf(ag, 0.f);
      cst1 = fmaf(gf, cst1, gi * gg);
      const float h = go * fmaxf(cst1, 0.f);
      if (sl1 == 0) h1c[buf][row][u1] = h;
    }

    // ---- LSTM2 recurrence (16 steps behind) ----
    if (r2) {
      const int row2 = s & 7, buf2 = (s >> 3) & 1;
      const float4* xv2 = (const float4*)&hb2[(s + 1) & 1][sl2 * 8];
      float zq2 = 0.f;
      if (sl2 < 4)
        zq2 = zx2[buf2][0][row2][sl2 * 64 + u2] + zx2[buf2][1][row2][sl2 * 64 + u2];
      float ai = (sl2 == 0) ? zq2 : 0.f;
      float af = (sl2 == 1) ? zq2 : 0.f;
      float ag = (sl2 == 2) ? zq2 : 0.f;
      float ao = (sl2 == 3) ? zq2 : 0.f;
      DOT32(xv2, w2, ai, af, ag, ao);
      ai = dpp_add_xor1(ai); af = dpp_add_xor1(af);
      ag = dpp_add_xor1(ag); ao = dpp_add_xor1(ao);
      ai = dpp_add_xor2(ai); af = dpp_add_xor2(af);
      ag = dpp_add_xor2(ag); ao = dpp_add_xor2(ao);
      ai = swz_add_xor4(ai); af = swz_add_xor4(af);
      ag = swz_add_xor4(ag); ao = swz_add_xor4(ao);
      const float gi = sigmoid_fast(ai);
      const float gf = sigmoid_fast(af);
      const float go = sigmoid_fast(ao);
      const float gg = fmaxf(ag, 0.f);
      cst2 = fmaf(gf, cst2, gi * gg);
      const float h2 = go * fmaxf(cst2, 0.f);
      if (sl2 == 0) {
        hb2[s & 1][u2] = h2;
        if (s == TT - 1) z_out[(size_t)b * 64 + u2] = h2;
      }
    }

    // ---- gemm1: zx1 chunk ch+1, k-slice [8j,8j+8) over 8 rows ----
    if (g1) {
      const float* base = xb + (size_t)(8 * (ch + 1)) * 64 + 8 * j;
      #pragma unroll
      for (int rg = 0; rg < 2; ++rg) {            // rows 0-3, then 4-7
        float4 xq[8];
        #pragma unroll
        for (int rr = 0; rr < 4; ++rr) {
          const float* p = base + (rg * 4 + rr) * 64;
          xq[2 * rr]     = *(const float4*)p;
          xq[2 * rr + 1] = *(const float4*)(p + 4);
        }
        #pragma unroll
        for (int rr = 0; rr < 4; ++rr) {
          float a = zxa[rg * 4 + rr];
          a = fmaf(xq[2*rr].x,   wk1r[0], a);
          a = fmaf(xq[2*rr].y,   wk1r[1], a);
          a = fmaf(xq[2*rr].z,   wk1r[2], a);
          a = fmaf(xq[2*rr].w,   wk1r[3], a);
          a = fmaf(xq[2*rr+1].x, wk1r[4], a);
          a = fmaf(xq[2*rr+1].y, wk1r[5], a);
          a = fmaf(xq[2*rr+1].z, wk1r[6], a);
          a = fmaf(xq[2*rr+1].w, wk1r[7], a);
          zxa[rg * 4 + rr] = a;
        }
      }
      if (j == 7) {
        #pragma unroll
        for (int r = 0; r < 8; ++r) {
          zx1[(ch + 1) & 1][r][c1] = zxa[r];
          zxa[r] = b1c;
        }
      }
    }

    // ---- gemm2: zx2 chunk ch-1 from h1c, K-half hf, k-slice 8 ----
    if (g2) {
      const int cc = ch - 1;
      #pragma unroll
      for (int r = 0; r < 8; ++r) {
        const float4 ha = *(const float4*)&h1c[cc & 1][r][hf * 64 + 8 * j];
        const float4 hbq = *(const float4*)&h1c[cc & 1][r][hf * 64 + 8 * j + 4];
        float a = zxa2[r];
        a = fmaf(ha.x,  wk2r[0], a);
        a = fmaf(ha.y,  wk2r[1], a);
        a = fmaf(ha.z,  wk2r[2], a);
        a = fmaf(ha.w,  wk2r[3], a);
        a = fmaf(hbq.x, wk2r[4], a);
        a = fmaf(hbq.y, wk2r[5], a);
        a = fmaf(hbq.z, wk2r[6], a);
        a = fmaf(hbq.w, wk2r[7], a);
        zxa2[r] = a;
      }
      if (j == 7) {
        #pragma unroll
        for (int r = 0; r < 8; ++r) {
          zx2[cc & 1][hf][r][c2] = zxa2[r];
          zxa2[r] = b2c;
        }
      }
    }

    if (t < 527) BARRIER();
  }
}

// ===========================================================================
// Decoder fused: LSTM3 (const-z RepeatVector -> 64, z@Wd1k folded once) +
// LSTM4 (64->128, 16 steps behind, input GEMM d1@Wd2k chunk-streamed) +
// TimeDistributed Dense 128->64 (r4-validated 2-stage pipeline).
// ===========================================================================
__global__ void __launch_bounds__(512, 2)
dec_fused(const float* __restrict__ zrow,  // [B,64]
          const float* __restrict__ Wd1k,  // [64,256]
          const float* __restrict__ Wd1r,  // [64,256]
          const float* __restrict__ bd1,   // [256]
          const float* __restrict__ Wd2k,  // [64,512]
          const float* __restrict__ Wd2r,  // [128,512]
          const float* __restrict__ bd2,   // [512]
          const float* __restrict__ Wout,  // [128,64]
          const float* __restrict__ boutp, // [64]
          float* __restrict__ out)         // [B,T,64]
{
  const int tid = (int)threadIdx.x, b = (int)blockIdx.x;
  const int l  = tid & 63, wv = tid >> 6;
  const int sl1 = l & 3,  u1 = wv * 16 + (l >> 2);   // LSTM4: NSu=4, H=128
  const int sl2 = l & 7,  u2 = wv * 8  + (l >> 3);   // LSTM3: NSu=8, H=64
  const int c3 = tid;                                 // gemm3 column (512)

  __shared__ __align__(16) float zx3[2][8][512];      // d1@Wd2k+bd2 (32 KB)
  __shared__ __align__(16) float hd1c[2][8][64];      // d1 h chunks (4 KB)
  __shared__ __align__(16) float hb2d[2][128];        // LSTM4 h ping-pong
  __shared__ __align__(16) float dp[2][512];          // dense partials
  __shared__ __align__(16) float zl[64];

  float w[32];                                        // Wd1r slice
  #pragma unroll
  for (int i = 0; i < 8; ++i) {
    const float* col = Wd1r + (size_t)(sl2 * 8 + i) * 256;
    #pragma unroll
    for (int g = 0; g < 4; ++g) w[i * 4 + g] = col[g * 64 + u2];
  }
  float w1[128];                                      // Wd2r slice
  #pragma unroll
  for (int i = 0; i < 32; ++i) {
    const float* col = Wd2r + (size_t)(sl1 * 32 + i) * 512;
    #pragma unroll
    for (int g = 0; g < 4; ++g) w1[i * 4 + g] = col[g * 128 + u1];
  }
  float wout_r[16];
  #pragma unroll
  for (int jj = 0; jj < 16; ++jj) wout_r[jj] = Wout[(size_t)(16 * wv + jj) * 64 + l];
  const float boutr = boutp[l];
  const float bd2c = bd2[c3];

  if (tid < 16) ((float4*)zl)[tid] = ((const float4*)(zrow + (size_t)b * 64))[tid];
  if (tid < 64)  hd1c[1][7][tid] = 0.f;
  if (tid < 128) hb2d[1][tid]   = 0.f;
  float zxa3[8];
  #pragma unroll
  for (int r = 0; r < 8; ++r) zxa3[r] = bd2c;
  BARRIER();

  // fold z@Wd1k once (per-lane slice partials; bd1 in lane sl2==0 only)
  float zi = (sl2 == 0) ? bd1[u2]        : 0.f;
  float zf = (sl2 == 0) ? bd1[64 + u2]   : 0.f;
  float zg = (sl2 == 0) ? bd1[128 + u2]  : 0.f;
  float zo = (sl2 == 0) ? bd1[192 + u2]  : 0.f;
  #pragma unroll
  for (int i = 0; i < 8; ++i) {
    const int k = sl2 * 8 + i;
    const float zv = zl[k];
    const float* col = Wd1k + (size_t)k * 256;
    zi = fmaf(zv, col[u2],        zi);
    zf = fmaf(zv, col[64 + u2],   zf);
    zg = fmaf(zv, col[128 + u2],  zg);
    zo = fmaf(zv, col[192 + u2],  zo);
  }

  float cst1 = 0.f, cst2 = 0.f;

  for (int t = -8; t < 530; ++t) {
    const int j  = t & 7;
    const int ch = t >> 3;
    const bool rd1 = (t >= 0 && t < TT);
    const bool g3  = (t >= 8 && t < 520);  // gemm3 builds chunk ch-1
    const int  s   = t - 16;
    const bool rd2 = (s >= 0 && s < TT);

    float wk3r[8];
    if (g3) {
      #pragma unroll
      for (int i = 0; i < 8; ++i) wk3r[i] = Wd2k[(size_t)(8 * j + i) * 512 + c3];
    }

    // ---- LSTM3 recurrence (const-z input folded in zi..zo) ----
    if (rd1) {
      const int row = t & 7,        buf  = ch & 1;
      const int prow = (t - 1) & 7, pbuf = ((t - 1) >> 3) & 1;
      const float4* xv = (const float4*)&hd1c[pbuf][prow][sl2 * 8];
      float ai = zi, af = zf, ag = zg, ao = zo;
      DOT32(xv, w, ai, af, ag, ao);
      ai = dpp_add_xor1(ai); af = dpp_add_xor1(af);
      ag = dpp_add_xor1(ag); ao = dpp_add_xor1(ao);
      ai = dpp_add_xor2(ai); af = dpp_add_xor2(af);
      ag = dpp_add_xor2(ag); ao = dpp_add_xor2(ao);
      ai = swz_add_xor4(ai); af = swz_add_xor4(af);
      ag = swz_add_xor4(ag); ao = swz_add_xor4(ao);
      const float gi = sigmoid_fast(ai);
      const float gf = sigmoid_fast(af);
      const float go = sigmoid_fast(ao);
      const float gg = fmaxf(ag, 0.f);
      cst1 = fmaf(gf, cst1, gi * gg);
      const float h = go * fmaxf(cst1, 0.f);
      if (sl2 == 0) hd1c[buf][row][u2] = h;
    }

    // ---- LSTM4 recurrence (16 behind) ----
    if (rd2) {
      const int row2 = s & 7, buf2 = (s >> 3) & 1;
      const float4* xv2 = (const float4*)&hb2d[(s + 1) & 1][sl1 * 32];
      const float zq = zx3[buf2][row2][sl1 * 128 + u1];
      float ai = (sl1 == 0) ? zq : 0.f;
      float af = (sl1 == 1) ? zq : 0.f;
      float ag = (sl1 == 2) ? zq : 0.f;
      float ao = (sl1 == 3) ? zq : 0.f;
      DOT128(xv2, w1, ai, af, ag, ao);
      ai = dpp_add_xor1(ai); af = dpp_add_xor1(af);
      ag = dpp_add_xor1(ag); ao = dpp_add_xor1(ao);
      ai = dpp_add_xor2(ai); af = dpp_add_xor2(af);
      ag = dpp_add_xor2(ag); ao = dpp_add_xor2(ao);
      const float gi = sigmoid_fast(ai);
      const float gf = sigmoid_fast(af);
      const float go = sigmoid_fast(ao);
      const float gg = fmaxf(ag, 0.f);
      cst2 = fmaf(gf, cst2, gi * gg);
      const float h2 = go * fmaxf(cst2, 0.f);
      if (sl1 == 0) hb2d[s & 1][u1] = h2;
    }

    // ---- dense partial of h4(s-1); reduce of h4(s-2) (r4 pattern) ----
    if (s >= 1 && s <= TT) {
      const float* hsrc = &hb2d[(s + 1) & 1][16 * wv];
      float a = 0.f;
      #pragma unroll
      for (int q = 0; q < 16; q += 4) {
        const float4 hv = *(const float4*)(hsrc + q);
        a = fmaf(hv.x, wout_r[q + 0], a);
        a = fmaf(hv.y, wout_r[q + 1], a);
        a = fmaf(hv.z, wout_r[q + 2], a);
        a = fmaf(hv.w, wout_r[q + 3], a);
      }
      dp[(s - 1) & 1][wv * 64 + l] = a;
    }
    if (s >= 2 && s <= TT + 1 && wv == 7) {
      const float* dq = dp[s & 1];
      float o = boutr;
      #pragma unroll
      for (int q = 0; q < 8; ++q) o += dq[q * 64 + l];
      out[((size_t)b * TT + (s - 2)) * 64 + l] = o;
    }

    // ---- gemm3: zx3 chunk ch-1 from hd1c, k-slice [8j,8j+8) ----
    if (g3) {
      const int cc = ch - 1;
      #pragma unroll
      for (int r = 0; r < 8; ++r) {
        const float4 ha  = *(const float4*)&hd1c[cc & 1][r][8 * j];
        const float4 hbq = *(const float4*)&hd1c[cc & 1][r][8 * j + 4];
        float a = zxa3[r];
        a = fmaf(ha.x,  wk3r[0], a);
        a = fmaf(ha.y,  wk3r[1], a);
        a = fmaf(ha.z,  wk3r[2], a);
        a = fmaf(ha.w,  wk3r[3], a);
        a = fmaf(hbq.x, wk3r[4], a);
        a = fmaf(hbq.y, wk3r[5], a);
        a = fmaf(hbq.z, wk3r[6], a);
        a = fmaf(hbq.w, wk3r[7], a);
        zxa3[r] = a;
      }
      if (j == 7) {
        #pragma unroll
        for (int r = 0; r < 8; ++r) {
          zx3[cc & 1][r][c3] = zxa3[r];
          zxa3[r] = bd2c;
        }
      }
    }

    if (t < 529) BARRIER();
  }
}

extern "C" void kernel_launch(void* const* d_in, const int* in_sizes, int n_in,
                              void* d_out, int out_size, void* d_ws, size_t ws_size,
                              hipStream_t stream) {
  const float* x    = (const float*)d_in[0];
  const float* Wk1  = (const float*)d_in[1];
  const float* Wr1  = (const float*)d_in[2];
  const float* b1   = (const float*)d_in[3];
  const float* Wk2  = (const float*)d_in[4];
  const float* Wr2  = (const float*)d_in[5];
  const float* b2   = (const float*)d_in[6];
  const float* Wd1k = (const float*)d_in[7];
  const float* Wd1r = (const float*)d_in[8];
  const float* bd1  = (const float*)d_in[9];
  const float* Wd2k = (const float*)d_in[10];
  const float* Wd2r = (const float*)d_in[11];
  const float* bd2  = (const float*)d_in[12];
  const float* Wout = (const float*)d_in[13];
  const float* bout = (const float*)d_in[14];
  float* out = (float*)d_out;

  // ws: only z [B,64] — always fits (>= 64 MB observed)
  if (ws_size < (size_t)BB * 64 * sizeof(float)) return;
  float* z = (float*)d_ws;

  enc_fused<<<BB, 512, 0, stream>>>(x, Wk1, Wr1, b1, Wk2, Wr2, b2, z);
  dec_fused<<<BB, 512, 0, stream>>>(z, Wd1k, Wd1r, bd1, Wd2k, Wd2r, bd2,
                                    Wout, bout, out);
}